// Round 5
// baseline (412.436 us; speedup 1.0000x reference)
//
#include <hip/hip_runtime.h>
#include <math.h>

#define NB 8192
#define NE 8
#define F1 1024
#define F2 2048
#define NC 100
#define NCP 112
#define TM 128
#define BK 32
#define NKT (F1 / BK)    // 32
#define NCC (F2 / 128)   // 16
#define MAXTY 72

#define WS_CUR   17
#define WS_TYE   32
#define WS_TYR   104
#define WS_TYN   176
#define WS_ROWS  256

#define OFF_XH  ((size_t)65536)
#define SZ_X    ((size_t)NB * F1)
#define OFF_W1H (OFF_XH + 4 * SZ_X)
#define SZ_W1   ((size_t)NE * F2 * F1)
#define OFF_W2H (OFF_W1H + 4 * SZ_W1)
#define SZ_W2   ((size_t)NE * NCP * F2)

typedef float f32x4 __attribute__((ext_vector_type(4)));
typedef short s16x8 __attribute__((ext_vector_type(8)));
typedef unsigned short u16x8 __attribute__((ext_vector_type(8)));
typedef unsigned short u16x4 __attribute__((ext_vector_type(4)));

__device__ __forceinline__ unsigned short bf_hi(float f) {
    unsigned u = __float_as_uint(f);
    return (unsigned short)((u + 0x7FFFu + ((u >> 16) & 1u)) >> 16);  // RNE
}
__device__ __forceinline__ float bf_up(unsigned short h) {
    return __uint_as_float(((unsigned)h) << 16);
}

typedef const __attribute__((address_space(1))) unsigned cgu;
typedef __attribute__((address_space(3))) unsigned ldu;
__device__ __forceinline__ void gl16(const void* g, void* l) {
    __builtin_amdgcn_global_load_lds((cgu*)g, (ldu*)l, 16, 0, 0);
}

// -------- planning: ballot histogram + ty table (no global atomics) --------
__global__ __launch_bounds__(512) void k_plan(const int* __restrict__ dom, int* ws) {
    __shared__ int wh[8][8];
    const int tid = threadIdx.x, wave = tid >> 6, lane = tid & 63;
    int cnt[NE];
#pragma unroll
    for (int e = 0; e < NE; ++e) cnt[e] = 0;
    for (int i = tid; i < NB / 4; i += 512) {
        int4 d = ((const int4*)dom)[i];
        int v[4] = {d.x, d.y, d.z, d.w};
#pragma unroll
        for (int t = 0; t < 4; ++t)
#pragma unroll
            for (int e = 0; e < NE; ++e)
                cnt[e] += (int)__popcll(__ballot(v[t] == e));
    }
    if (lane == 0)
#pragma unroll
        for (int e = 0; e < NE; ++e) wh[wave][e] = cnt[e];
    __syncthreads();
    if (tid == 0) {
        int c[NE], off = 0, ty = 0;
        for (int e = 0; e < NE; ++e) {
            c[e] = 0;
            for (int w = 0; w < 8; ++w) c[e] += wh[w][e];
        }
        for (int e = 0; e < NE; ++e) {
            ws[WS_CUR + e] = off;
            int nt = (c[e] + TM - 1) / TM;
            for (int t = 0; t < nt; ++t) {
                ws[WS_TYE + ty] = e;
                ws[WS_TYR + ty] = off + t * TM;
                ws[WS_TYN + ty] = min(TM, c[e] - t * TM);
                ++ty;
            }
            off += c[e];
        }
        for (; ty < MAXTY; ++ty) ws[WS_TYN + ty] = 0;
    }
}

__global__ __launch_bounds__(256) void k_scatter(const int* __restrict__ dom, int* ws) {
    __shared__ int lh[NE], base[NE];
    const int tid = threadIdx.x;
    if (tid < NE) lh[tid] = 0;
    __syncthreads();
    const int b = blockIdx.x * 256 + tid;
    const int e = dom[b];
    const int r = atomicAdd(&lh[e], 1);
    __syncthreads();
    if (tid < NE) base[tid] = atomicAdd(&ws[WS_CUR + tid], lh[tid]);
    __syncthreads();
    ws[WS_ROWS + base[e] + r] = b;
}

// -------- fused pre-pass: x split | W1 transpose+split | W2 transpose+split --------
__global__ __launch_bounds__(256) void k_prep(
    const float* __restrict__ x, const float* __restrict__ W1,
    const float* __restrict__ W2, unsigned short* __restrict__ xh,
    unsigned short* __restrict__ w1h, unsigned short* __restrict__ w2h)
{
    __shared__ float t[64 * 101];
    const int bx = blockIdx.x;
    if (bx < 2048) {                       // ---- x: 4096 floats per block ----
        unsigned short* xl = xh + SZ_X;
#pragma unroll
        for (int q = 0; q < 4; ++q) {
            size_t i = (size_t)bx * 1024 + q * 256 + threadIdx.x;
            float4 v = *(const float4*)(x + i * 4);
            u16x4 h, l;
            float f[4] = {v.x, v.y, v.z, v.w};
#pragma unroll
            for (int c = 0; c < 4; ++c) {
                unsigned short hh = bf_hi(f[c]);
                h[c] = hh;
                l[c] = bf_hi(f[c] - bf_up(hh));
            }
            *(u16x4*)(xh + i * 4) = h;
            *(u16x4*)(xl + i * 4) = l;
        }
    } else if (bx < 2048 + 4096) {         // ---- W1 64x64 tile transpose ----
        unsigned short* w1l = w1h + SZ_W1;
        const int tt = bx - 2048;
        const int e = tt >> 9, rem = tt & 511;
        const int k0 = (rem >> 5) * 64, n0 = (rem & 31) * 64;
        const float* src = W1 + ((size_t)e * F1 + k0) * F2 + n0;
#pragma unroll
        for (int i = 0; i < 4; ++i) {
            int u = threadIdx.x + 256 * i;
            int k = u >> 4, n4 = (u & 15) * 4;
            float4 v = *(const float4*)(src + (size_t)k * F2 + n4);
            t[k * 65 + n4] = v.x; t[k * 65 + n4 + 1] = v.y;
            t[k * 65 + n4 + 2] = v.z; t[k * 65 + n4 + 3] = v.w;
        }
        __syncthreads();
#pragma unroll
        for (int i = 0; i < 2; ++i) {
            int u = threadIdx.x + 256 * i;
            int n = u >> 3, kg = u & 7;
            u16x8 hv, lv;
#pragma unroll
            for (int j = 0; j < 8; ++j) {
                float v = t[(kg * 8 + j) * 65 + n];
                unsigned short hh = bf_hi(v);
                hv[j] = hh;
                lv[j] = bf_hi(v - bf_up(hh));
            }
            size_t dst = ((size_t)e * F2 + n0 + n) * F1 + k0 + kg * 8;
            *(u16x8*)(w1h + dst) = hv;
            *(u16x8*)(w1l + dst) = lv;
        }
    } else {                               // ---- W2 64-row transpose ----
        unsigned short* w2l = w2h + SZ_W2;
        const int tt = bx - 6144;
        const int e = tt >> 5, k0 = (tt & 31) * 64;
        const float* src = W2 + ((size_t)e * F2 + k0) * NC;
        for (int u = threadIdx.x; u < 64 * NC; u += 256) {
            int k = u / NC, c = u - k * NC;
            t[k * 101 + c] = src[u];
        }
        __syncthreads();
#pragma unroll
        for (int i = 0; i < 4; ++i) {
            int u = threadIdx.x + 256 * i;
            if (u < NCP * 8) {
                int c = u >> 3, kg = u & 7;
                u16x8 hv, lv;
#pragma unroll
                for (int j = 0; j < 8; ++j) {
                    float v = (c < NC) ? t[(kg * 8 + j) * 101 + c] : 0.f;
                    unsigned short hh = bf_hi(v);
                    hv[j] = hh;
                    lv[j] = bf_hi(v - bf_up(hh));
                }
                size_t dst = ((size_t)e * NCP + c) * F2 + k0 + kg * 8;
                *(u16x8*)(w2h + dst) = hv;
                *(u16x8*)(w2l + dst) = lv;
            }
        }
    }
}

// -------- fused grouped GEMM: dbuf + counted vmcnt, unit-contiguous LDS --------
// Phase-A unit u = b*64 + s*16 + i  (row r=b*16+i, k-slot s); LDS off = u*8 ushorts.
// Per buf d at d*16384: Ah+0, Al+4096, Bh+8192, Bl+12288.
__global__ __launch_bounds__(256, 2) void k_g1(
    const int* __restrict__ ws, const unsigned short* __restrict__ xh,
    const unsigned short* __restrict__ w1h, const unsigned short* __restrict__ w2h,
    const float* __restrict__ b1, float* __restrict__ out)
{
    __shared__ __align__(16) unsigned short sb[32768];
    __shared__ int rows[TM];
    const int tid = threadIdx.x;
    const int cc = blockIdx.x;
    const int ty = blockIdx.y;

    const int nr = ws[WS_TYN + ty];
    if (nr <= 0) return;
    const int e = ws[WS_TYE + ty];
    const int rbase = ws[WS_TYR + ty];
    if (tid < TM) rows[tid] = ws[WS_ROWS + rbase + min(tid, nr - 1)];
    __syncthreads();

    const int wave = tid >> 6, lane = tid & 63;
    const int wm = wave >> 1, wn = wave & 1;
    const int lg = lane >> 4, ln = lane & 15;
    const int l7 = ln & 7;

    // staging: thread handles units u=tid, tid+256; u -> (r=b*16+i, s)
    const unsigned short* pA[2];
    const unsigned short* pB[2];
#pragma unroll
    for (int i = 0; i < 2; ++i) {
        int u = tid + 256 * i;
        int r = (u >> 6) * 16 + (u & 15), s = (u >> 4) & 3;
        pA[i] = xh + (size_t)rows[r] * F1 + s * 8;
        pB[i] = w1h + ((size_t)e * F2 + cc * 128 + r) * F1 + s * 8;
    }
    const int ldst0 = tid * 8;
    const int ldst1 = ldst0 + 2048;

    float bias[4];
#pragma unroll
    for (int nf = 0; nf < 4; ++nf)
        bias[nf] = b1[e * F2 + cc * 128 + wn * 64 + nf * 16 + ln];

    // fragment read offsets (contiguous 1KB per wave-read -> conflict-free)
    int aoff[4], boff[4];
#pragma unroll
    for (int m = 0; m < 4; ++m) aoff[m] = (wm * 4 + m) * 512 + lg * 128 + ln * 8;
#pragma unroll
    for (int n = 0; n < 4; ++n) boff[n] = 8192 + (wn * 4 + n) * 512 + lg * 128 + ln * 8;

    f32x4 acc[4][4];
#pragma unroll
    for (int m = 0; m < 4; ++m)
#pragma unroll
        for (int n = 0; n < 4; ++n) acc[m][n] = (f32x4){0.f, 0.f, 0.f, 0.f};

#define STAGE(kt, db)                                                          \
    {                                                                          \
        const int ko = (kt) * BK;                                              \
        const int b0 = (db) * 16384;                                           \
        gl16(pA[0] + ko,         &sb[b0 + ldst0]);                             \
        gl16(pA[1] + ko,         &sb[b0 + ldst1]);                             \
        gl16(pA[0] + SZ_X + ko,  &sb[b0 + 4096 + ldst0]);                      \
        gl16(pA[1] + SZ_X + ko,  &sb[b0 + 4096 + ldst1]);                      \
        gl16(pB[0] + ko,         &sb[b0 + 8192 + ldst0]);                      \
        gl16(pB[1] + ko,         &sb[b0 + 8192 + ldst1]);                      \
        gl16(pB[0] + SZ_W1 + ko, &sb[b0 + 12288 + ldst0]);                     \
        gl16(pB[1] + SZ_W1 + ko, &sb[b0 + 12288 + ldst1]);                     \
    }

    STAGE(0, 0);
    for (int kt = 0; kt < NKT; ++kt) {
        const int cur = kt & 1;
        if (kt + 1 < NKT) {
            STAGE(kt + 1, cur ^ 1);
            asm volatile("s_waitcnt vmcnt(8)" ::: "memory");
        } else {
            asm volatile("s_waitcnt vmcnt(0)" ::: "memory");
        }
        __builtin_amdgcn_s_barrier();
        __builtin_amdgcn_sched_barrier(0);
        const int b0 = cur * 16384;
        s16x8 ah[4], al[4];
#pragma unroll
        for (int m = 0; m < 4; ++m) {
            ah[m] = *(const s16x8*)&sb[b0 + aoff[m]];
            al[m] = *(const s16x8*)&sb[b0 + 4096 + aoff[m]];
        }
#pragma unroll
        for (int n = 0; n < 4; ++n) {
            s16x8 bh = *(const s16x8*)&sb[b0 + boff[n]];
            s16x8 bl = *(const s16x8*)&sb[b0 + 4096 + boff[n]];
#pragma unroll
            for (int m = 0; m < 4; ++m) {
                acc[m][n] = __builtin_amdgcn_mfma_f32_16x16x32_bf16(ah[m], bh, acc[m][n], 0, 0, 0);
                acc[m][n] = __builtin_amdgcn_mfma_f32_16x16x32_bf16(al[m], bh, acc[m][n], 0, 0, 0);
                acc[m][n] = __builtin_amdgcn_mfma_f32_16x16x32_bf16(ah[m], bl, acc[m][n], 0, 0, 0);
            }
        }
        __builtin_amdgcn_sched_barrier(0);
        __builtin_amdgcn_s_barrier();
    }
#undef STAGE

    // ---- phase B: logits partials = relu(h + b1) @ W2t ----
    f32x4 acc2[2][7];
#pragma unroll
    for (int mf = 0; mf < 2; ++mf)
#pragma unroll
        for (int cf = 0; cf < 7; ++cf) acc2[mf][cf] = (f32x4){0.f, 0.f, 0.f, 0.f};

#pragma unroll
    for (int s = 0; s < 2; ++s) {
        __syncthreads();
        if (wn == s) {
#pragma unroll
            for (int m = 0; m < 4; ++m)
#pragma unroll
                for (int nf = 0; nf < 4; ++nf) {
                    const float bb = bias[nf];
                    const int k2 = nf * 16 + ln;
#pragma unroll
                    for (int reg = 0; reg < 4; ++reg) {
                        int row = wm * 64 + m * 16 + lg * 4 + reg;
                        float v = fmaxf(acc[m][nf][reg] + bb, 0.f);
                        unsigned short hh = bf_hi(v);
                        int off = row * 64 + ((k2 >> 3) ^ (row & 7)) * 8 + (k2 & 7);
                        sb[off] = hh;
                        sb[8192 + off] = bf_hi(v - bf_up(hh));
                    }
                }
        }
        for (int ch = wave; ch < 14; ch += 4) {
            int u = ch * 64 + lane;
            int c = u >> 3, g = u & 7;
            const unsigned short* src =
                w2h + ((size_t)e * NCP + c) * F2 + cc * 128 + s * 64 + ((g ^ (c & 7)) * 8);
            gl16(src,         &sb[16384 + ch * 512]);
            gl16(src + SZ_W2, &sb[24576 + ch * 512]);
        }
        __syncthreads();
#pragma unroll
        for (int kk = 0; kk < 2; ++kk) {
            const int sz = (kk * 4 + lg) ^ l7;
            s16x8 hh[2], hl[2];
#pragma unroll
            for (int mf = 0; mf < 2; ++mf) {
                int off = (wave * 32 + mf * 16 + ln) * 64 + sz * 8;
                hh[mf] = *(const s16x8*)&sb[off];
                hl[mf] = *(const s16x8*)&sb[8192 + off];
            }
#pragma unroll
            for (int cf = 0; cf < 7; ++cf) {
                int off = (cf * 16 + ln) * 64 + sz * 8;
                s16x8 wh = *(const s16x8*)&sb[16384 + off];
                s16x8 wl = *(const s16x8*)&sb[24576 + off];
#pragma unroll
                for (int mf = 0; mf < 2; ++mf) {
                    acc2[mf][cf] = __builtin_amdgcn_mfma_f32_16x16x32_bf16(hh[mf], wh, acc2[mf][cf], 0, 0, 0);
                    acc2[mf][cf] = __builtin_amdgcn_mfma_f32_16x16x32_bf16(hl[mf], wh, acc2[mf][cf], 0, 0, 0);
                    acc2[mf][cf] = __builtin_amdgcn_mfma_f32_16x16x32_bf16(hh[mf], wl, acc2[mf][cf], 0, 0, 0);
                }
            }
        }
    }

#pragma unroll
    for (int mf = 0; mf < 2; ++mf)
#pragma unroll
        for (int cf = 0; cf < 7; ++cf)
#pragma unroll
            for (int reg = 0; reg < 4; ++reg) {
                int row = wave * 32 + mf * 16 + lg * 4 + reg;
                int c = cf * 16 + ln;
                if (row < nr && c < NC)
                    atomicAdd(out + (size_t)rows[row] * NC + c, acc2[mf][cf][reg]);
            }
}

__global__ void k_sm(const int* __restrict__ dom, const float* __restrict__ b2,
                     float* __restrict__ out)
{
    const int row = blockIdx.x * 4 + (threadIdx.x >> 6);
    const int lane = threadIdx.x & 63;
    const int e = dom[row];
    float* base = out + (size_t)row * NC;
    float v0 = base[lane] + b2[e * NC + lane];
    float v1 = -1e30f;
    if (lane + 64 < NC) v1 = base[lane + 64] + b2[e * NC + lane + 64];
    float m = fmaxf(v0, v1);
#pragma unroll
    for (int s = 1; s < 64; s <<= 1) m = fmaxf(m, __shfl_xor(m, s));
    float p0 = expf(v0 - m);
    float p1 = (lane + 64 < NC) ? expf(v1 - m) : 0.f;
    float sum = p0 + p1;
#pragma unroll
    for (int s = 1; s < 64; s <<= 1) sum += __shfl_xor(sum, s);
    float inv = 1.f / sum;
    base[lane] = p0 * inv;
    if (lane + 64 < NC) base[lane + 64] = p1 * inv;
}

extern "C" void kernel_launch(void* const* d_in, const int* in_sizes, int n_in,
                              void* d_out, int out_size, void* d_ws, size_t ws_size,
                              hipStream_t stream)
{
    const int*   dom = (const int*)d_in[0];
    const float* x   = (const float*)d_in[1];
    const float* W1  = (const float*)d_in[2];
    const float* b1  = (const float*)d_in[3];
    const float* W2  = (const float*)d_in[4];
    const float* b2  = (const float*)d_in[5];
    float*       out = (float*)d_out;
    int*         ws  = (int*)d_ws;

    unsigned short* xh  = (unsigned short*)((char*)d_ws + OFF_XH);
    unsigned short* w1h = (unsigned short*)((char*)d_ws + OFF_W1H);
    unsigned short* w2h = (unsigned short*)((char*)d_ws + OFF_W2H);

    hipMemsetAsync(out, 0, (size_t)NB * NC * sizeof(float), stream);
    hipLaunchKernelGGL(k_plan,    dim3(1), dim3(512), 0, stream, dom, ws);
    hipLaunchKernelGGL(k_scatter, dim3(NB / 256), dim3(256), 0, stream, dom, ws);
    hipLaunchKernelGGL(k_prep,    dim3(2048 + 4096 + 256), dim3(256), 0, stream,
                       x, W1, W2, xh, w1h, w2h);
    hipLaunchKernelGGL(k_g1,      dim3(NCC, MAXTY), dim3(256), 0, stream,
                       ws, xh, w1h, w2h, b1, out);
    hipLaunchKernelGGL(k_sm,      dim3(NB / 4), dim3(256), 0, stream, dom, b2, out);
}